// Round 1
// baseline (1479.732 us; speedup 1.0000x reference)
//
#include <hip/hip_runtime.h>
#include <math.h>

#define BB 4
#define LL 512
#define D0 640
#define PP 128
#define CC 32
#define NLAYER 3
#define NN (BB*LL)      // 2048
#define RADIN 130
#define WPB 4           // edges (waves) per block in edge kernel

// ---------------- utility kernels ----------------

__global__ void k_zero_int(int* __restrict__ p, int n) {
    int i = blockIdx.x * blockDim.x + threadIdx.x;
    if (i < n) p[i] = 0;
}

// h0 = seq_rep @ Win0   (one wave per node; lanes 0..31 chan, halves split K)
__global__ __launch_bounds__(64) void k_init_h0(const float* __restrict__ seq,
                                                const float* __restrict__ Win0,
                                                float* __restrict__ h0) {
    const int n = blockIdx.x, lane = threadIdx.x;
    const int c = lane & 31, half = lane >> 5;
    const float* s = seq + (size_t)n * D0;
    float acc = 0.f;
    const int i0 = half * (D0 / 2), i1 = i0 + (D0 / 2);
    for (int i = i0; i < i1; ++i) acc = fmaf(s[i], Win0[i * CC + c], acc);
    acc += __shfl_xor(acc, 32);
    if (lane < 32) h0[n * CC + c] = acc;
}

// h1[n,c,d] = x[n,d] * Win1[c]
__global__ void k_init_h1(const float* __restrict__ x, const float* __restrict__ Win1,
                          float* __restrict__ h1) {
    int idx = blockIdx.x * blockDim.x + threadIdx.x;
    if (idx >= NN * CC) return;
    int n = idx >> 5, c = idx & 31;
    float w = Win1[c];
    const float* xp = x + n * 3;
    float* hp = h1 + (size_t)n * 96 + c * 3;
    hp[0] = xp[0] * w; hp[1] = xp[1] * w; hp[2] = xp[2] * w;
}

// per-edge geometry: r, rhat
__global__ void k_geom(const int* __restrict__ src, const int* __restrict__ dst,
                       const float* __restrict__ x, float* __restrict__ r_e,
                       float* __restrict__ rhat, int E) {
    int e = blockIdx.x * blockDim.x + threadIdx.x;
    if (e >= E) return;
    int s = src[e], d = dst[e];
    float dx = x[d * 3 + 0] - x[s * 3 + 0];
    float dy = x[d * 3 + 1] - x[s * 3 + 1];
    float dz = x[d * 3 + 2] - x[s * 3 + 2];
    float r = sqrtf(dx * dx + dy * dy + dz * dz + 1e-12f);
    float ir = 1.f / (r + 1e-8f);
    r_e[e] = r;
    rhat[e * 3 + 0] = dx * ir; rhat[e * 3 + 1] = dy * ir; rhat[e * 3 + 2] = dz * ir;
}

__global__ void k_count(const int* __restrict__ dst, int* __restrict__ deg, int E) {
    int e = blockIdx.x * blockDim.x + threadIdx.x;
    if (e < E) atomicAdd(&deg[dst[e]], 1);
}

// exclusive scan over N=2048 degrees with one wave; also zero cursor
__global__ __launch_bounds__(64) void k_scan(const int* __restrict__ deg,
                                             int* __restrict__ rowptr,
                                             int* __restrict__ cursor) {
    const int lane = threadIdx.x;          // 0..63
    const int base = lane * 32;            // 64*32 = 2048
    int loc[32]; int s = 0;
    for (int i = 0; i < 32; ++i) { loc[i] = deg[base + i]; s += loc[i]; }
    int pre = s;
    for (int off = 1; off < 64; off <<= 1) {
        int t = __shfl_up(pre, off);
        if (lane >= off) pre += t;
    }
    pre -= s;                              // exclusive prefix of this lane's chunk
    int run = pre;
    for (int i = 0; i < 32; ++i) { rowptr[base + i] = run; cursor[base + i] = 0; run += loc[i]; }
    if (lane == 63) rowptr[NN] = run;
}

__global__ void k_scatter(const int* __restrict__ dst, const int* __restrict__ rowptr,
                          int* __restrict__ cursor, int* __restrict__ einc, int E) {
    int e = blockIdx.x * blockDim.x + threadIdx.x;
    if (e >= E) return;
    int d = dst[e];
    int pos = atomicAdd(&cursor[d], 1);
    einc[rowptr[d] + pos] = e;
}

// ---------------- edge message kernel (per layer) ----------------
// one wave per edge, WPB waves per block
__global__ __launch_bounds__(64 * WPB) void k_edge_msg(
    int l, int E,
    const int* __restrict__ src, const int* __restrict__ dst,
    const float* __restrict__ pair, const float* __restrict__ bppm,
    const float* __restrict__ r_e, const float* __restrict__ rhat,
    const float* __restrict__ h0, const float* __restrict__ h1,
    const float* __restrict__ Wr1, const float* __restrict__ br1,
    const float* __restrict__ Wr2, const float* __restrict__ br2,
    const float* __restrict__ Wm00, const float* __restrict__ Wm01,
    const float* __restrict__ Wm10, const float* __restrict__ Wm11,
    float* __restrict__ m0buf, float* __restrict__ m1buf)
{
    __shared__ float lds[WPB][516];
    const int wave = threadIdx.x >> 6, lane = threadIdx.x & 63;
    const int e = blockIdx.x * WPB + wave;
    const bool act = (e < E);
    float* S = lds[wave];
    float* s_ef  = S;        // 130 (reused for v11 in phase 4)
    float* s_hid = S + 132;  // 64
    float* s_h0  = S + 196;  // 32
    float* s_h1  = S + 228;  // 96
    float* s_dot = S + 324;  // 32
    float* s_rad = S + 356;  // 128

    int sidx = 0;
    float rh0 = 0.f, rh1 = 0.f, rh2 = 0.f;
    if (act) {
        sidx = src[e];
        int didx = dst[e];
        int b = sidx / LL, si = sidx % LL, di = didx % LL;
        size_t prow = ((size_t)b * LL + si) * LL + di;
        const float* pr = pair + prow * PP;
        s_ef[lane] = pr[lane];
        s_ef[64 + lane] = pr[64 + lane];
        if (lane == 0) { s_ef[128] = bppm[prow]; s_ef[129] = r_e[e]; }
        s_h1[lane] = h1[(size_t)sidx * 96 + lane];
        if (lane < 32) {
            s_h1[64 + lane] = h1[(size_t)sidx * 96 + 64 + lane];
            s_h0[lane] = h0[sidx * CC + lane];
        }
        rh0 = rhat[e * 3 + 0]; rh1 = rhat[e * 3 + 1]; rh2 = rhat[e * 3 + 2];
    }
    __syncthreads();

    // radial hidden layer: 130 -> 64, relu
    if (act) {
        float hid = br1[l * 64 + lane];
        const float* W = Wr1 + (size_t)l * RADIN * 64;
        for (int i = 0; i < RADIN; ++i) hid = fmaf(s_ef[i], W[i * 64 + lane], hid);
        s_hid[lane] = fmaxf(hid, 0.f);
    }
    __syncthreads();

    // radial output: 64 -> 128 ; + dot1 by lanes<32
    if (act) {
        float ra = br2[l * 128 + lane], rb = br2[l * 128 + 64 + lane];
        const float* W = Wr2 + (size_t)l * 64 * 128;
        for (int i = 0; i < 64; ++i) {
            float h = s_hid[i];
            ra = fmaf(h, W[i * 128 + lane], ra);
            rb = fmaf(h, W[i * 128 + 64 + lane], rb);
        }
        s_rad[lane] = ra; s_rad[64 + lane] = rb;
        if (lane < 32) {
            s_dot[lane] = s_h1[lane * 3 + 0] * rh0 + s_h1[lane * 3 + 1] * rh1
                        + s_h1[lane * 3 + 2] * rh2;
        }
    }
    __syncthreads();

    float u10 = 0.f;
    if (act) {
        if (lane < 32) {
            const int c = lane;
            const float* W00 = Wm00 + l * 1024;
            const float* W01 = Wm01 + l * 1024;
            const float* W10 = Wm10 + l * 1024;
            float t0 = 0.f, t1 = 0.f, t2 = 0.f;
            for (int i = 0; i < 32; ++i) {
                float a0 = s_h0[i];
                t0 = fmaf(a0, W00[i * 32 + c], t0);
                t1 = fmaf(s_dot[i], W01[i * 32 + c], t1);
                t2 = fmaf(a0, W10[i * 32 + c], t2);
            }
            m0buf[(size_t)e * 32 + c] = s_rad[c] * t0 + s_rad[32 + c] * t1;
            u10 = s_rad[64 + c] * t2;
        } else {
            const int c = lane - 32;
            const float* W11 = Wm11 + l * 1024;
            float v0 = 0.f, v1 = 0.f, v2 = 0.f;
            for (int i = 0; i < 32; ++i) {
                float w = W11[i * 32 + c];
                v0 = fmaf(s_h1[i * 3 + 0], w, v0);
                v1 = fmaf(s_h1[i * 3 + 1], w, v1);
                v2 = fmaf(s_h1[i * 3 + 2], w, v2);
            }
            s_ef[c * 3 + 0] = v0; s_ef[c * 3 + 1] = v1; s_ef[c * 3 + 2] = v2;
        }
    }
    __syncthreads();
    if (act && lane < 32) {
        const int c = lane;
        float w11 = s_rad[96 + c];
        float* mp = m1buf + (size_t)e * 96 + c * 3;
        mp[0] = fmaf(w11, s_ef[c * 3 + 0], u10 * rh0);
        mp[1] = fmaf(w11, s_ef[c * 3 + 1], u10 * rh1);
        mp[2] = fmaf(w11, s_ef[c * 3 + 2], u10 * rh2);
    }
}

// ---------------- node update kernel (per layer) ----------------
// one wave per node; halves process two incoming edges per iteration
__global__ __launch_bounds__(64) void k_node(
    int l, const int* __restrict__ rowptr, const int* __restrict__ einc,
    const float* __restrict__ m0buf, const float* __restrict__ m1buf,
    float* __restrict__ h0, float* __restrict__ h1,
    const float* __restrict__ Wq, const float* __restrict__ Ws0,
    const float* __restrict__ Ws1, const float* __restrict__ gam0,
    const float* __restrict__ bet0, const float* __restrict__ gam1)
{
    const int n = blockIdx.x, lane = threadIdx.x;
    const int c = lane & 31, half = lane >> 5;
    __shared__ float s_h0[32], s_a0[32], s_a1[96];
    if (lane < 32) s_h0[lane] = h0[n * CC + lane];
    __syncthreads();

    // q for this node's channel c (redundant across halves)
    float qc = 0.f;
    {
        const float* W = Wq + l * 1024;
        for (int i = 0; i < 32; ++i) qc = fmaf(s_h0[i], W[i * 32 + c], qc);
    }

    float m_run = -INFINITY, l_run = 0.f;
    float a0 = 0.f, a1x = 0.f, a1y = 0.f, a1z = 0.f;
    const int st = rowptr[n], en = rowptr[n + 1];
    for (int i = st; i < en; i += 2) {
        const int idx = i + half;
        const bool valid = idx < en;
        float kc = 0.f, mv0 = 0.f, mv1 = 0.f, mv2 = 0.f;
        if (valid) {
            const int e = einc[idx];
            kc = m0buf[(size_t)e * 32 + c];
            const float* mp = m1buf + (size_t)e * 96 + c * 3;
            mv0 = mp[0]; mv1 = mp[1]; mv2 = mp[2];
        }
        float p = qc * kc;
        p += __shfl_xor(p, 1); p += __shfl_xor(p, 2); p += __shfl_xor(p, 4);
        if (valid) {
            float logit = p * 0.35355339059327373f;   // 1/sqrt(8)
            float mn = fmaxf(m_run, logit);
            float sc = __expf(m_run - mn);
            float w  = __expf(logit - mn);
            l_run = fmaf(l_run, sc, w);
            a0  = fmaf(a0,  sc, w * kc);
            a1x = fmaf(a1x, sc, w * mv0);
            a1y = fmaf(a1y, sc, w * mv1);
            a1z = fmaf(a1z, sc, w * mv2);
            m_run = mn;
        }
    }
    // merge halves
    float m_o  = __shfl_xor(m_run, 32), l_o = __shfl_xor(l_run, 32);
    float a0o  = __shfl_xor(a0, 32);
    float a1xo = __shfl_xor(a1x, 32), a1yo = __shfl_xor(a1y, 32), a1zo = __shfl_xor(a1z, 32);
    float mn = fmaxf(m_run, m_o);
    float sa = 0.f, sb = 0.f;
    if (mn > -INFINITY) { sa = __expf(m_run - mn); sb = __expf(m_o - mn); }
    float den = l_run * sa + l_o * sb;
    float inv = 1.0f / (den + 1e-9f);
    float g0c = (a0  * sa + a0o  * sb) * inv;
    float g1x = (a1x * sa + a1xo * sb) * inv;
    float g1y = (a1y * sa + a1yo * sb) * inv;
    float g1z = (a1z * sa + a1zo * sb) * inv;
    if (lane < 32) {
        s_a0[c] = g0c;
        s_a1[c * 3 + 0] = g1x; s_a1[c * 3 + 1] = g1y; s_a1[c * 3 + 2] = g1z;
    }
    __syncthreads();

    // h0 self-interaction + LayerNorm (redundant across halves, lanes<32 write)
    float x0 = s_h0[c];
    {
        const float* W = Ws0 + l * 1024;
        for (int i = 0; i < 32; ++i) x0 = fmaf(s_a0[i], W[i * 32 + c], x0);
    }
    float mu = x0;
    mu += __shfl_xor(mu, 1); mu += __shfl_xor(mu, 2); mu += __shfl_xor(mu, 4);
    mu += __shfl_xor(mu, 8); mu += __shfl_xor(mu, 16);
    mu *= (1.f / 32.f);
    float sq = x0 * x0;
    sq += __shfl_xor(sq, 1); sq += __shfl_xor(sq, 2); sq += __shfl_xor(sq, 4);
    sq += __shfl_xor(sq, 8); sq += __shfl_xor(sq, 16);
    float var = sq * (1.f / 32.f) - mu * mu;
    float h0n = (x0 - mu) * rsqrtf(var + 1e-5f) * gam0[l * 32 + c] + bet0[l * 32 + c];
    if (lane < 32) h0[n * CC + c] = h0n;

    // h1 self-interaction + equivariant norm gate
    const float* hp = h1 + (size_t)n * 96 + c * 3;
    float v0 = hp[0], v1 = hp[1], v2 = hp[2];
    {
        const float* W = Ws1 + l * 1024;
        for (int i = 0; i < 32; ++i) {
            float w = W[i * 32 + c];
            v0 = fmaf(s_a1[i * 3 + 0], w, v0);
            v1 = fmaf(s_a1[i * 3 + 1], w, v1);
            v2 = fmaf(s_a1[i * 3 + 2], w, v2);
        }
    }
    float nrm = sqrtf(v0 * v0 + v1 * v1 + v2 * v2 + 1e-12f);
    float mu2 = nrm;
    mu2 += __shfl_xor(mu2, 1); mu2 += __shfl_xor(mu2, 2); mu2 += __shfl_xor(mu2, 4);
    mu2 += __shfl_xor(mu2, 8); mu2 += __shfl_xor(mu2, 16);
    mu2 *= (1.f / 32.f);
    float sq2 = nrm * nrm;
    sq2 += __shfl_xor(sq2, 1); sq2 += __shfl_xor(sq2, 2); sq2 += __shfl_xor(sq2, 4);
    sq2 += __shfl_xor(sq2, 8); sq2 += __shfl_xor(sq2, 16);
    float var2 = sq2 * (1.f / 32.f) - mu2 * mu2;
    float nln = (nrm - mu2) * rsqrtf(var2 + 1e-5f) * gam1[l * 32 + c];
    float scl = nln / (nrm + 1e-8f);
    if (lane < 32) {
        float* hw = h1 + (size_t)n * 96 + c * 3;
        hw[0] = v0 * scl; hw[1] = v1 * scl; hw[2] = v2 * scl;
    }
}

// ---------------- output kernel ----------------
__global__ void k_out(const float* __restrict__ x, const float* __restrict__ h1,
                      const float* __restrict__ Wout, float* __restrict__ out) {
    int idx = blockIdx.x * blockDim.x + threadIdx.x;   // N*3
    if (idx >= NN * 3) return;
    int n = idx / 3, d = idx % 3;
    float acc = x[idx];
    const float* hp = h1 + (size_t)n * 96 + d;
    for (int cc = 0; cc < 32; ++cc) acc = fmaf(hp[cc * 3], Wout[cc], acc);
    out[idx] = acc;
}

// ---------------- launch ----------------
extern "C" void kernel_launch(void* const* d_in, const int* in_sizes, int n_in,
                              void* d_out, int out_size, void* d_ws, size_t ws_size,
                              hipStream_t stream) {
    const float* seq  = (const float*)d_in[0];
    const float* pair = (const float*)d_in[1];
    const float* bppm = (const float*)d_in[2];
    const float* x    = (const float*)d_in[3];
    const int*   src  = (const int*)d_in[4];
    const int*   dst  = (const int*)d_in[5];
    const float* Win0 = (const float*)d_in[6];
    const float* Win1 = (const float*)d_in[7];
    const float* Wr1  = (const float*)d_in[8];
    const float* br1  = (const float*)d_in[9];
    const float* Wr2  = (const float*)d_in[10];
    const float* br2  = (const float*)d_in[11];
    const float* Wm00 = (const float*)d_in[12];
    const float* Wm01 = (const float*)d_in[13];
    const float* Wm10 = (const float*)d_in[14];
    const float* Wm11 = (const float*)d_in[15];
    const float* Wq   = (const float*)d_in[16];
    const float* Ws0  = (const float*)d_in[17];
    const float* Ws1  = (const float*)d_in[18];
    const float* gam0 = (const float*)d_in[19];
    const float* bet0 = (const float*)d_in[20];
    const float* gam1 = (const float*)d_in[21];
    const float* Wout = (const float*)d_in[22];
    const int E = in_sizes[4];

    char* w = (char*)d_ws;
    auto alloc = [&](size_t nbytes) {
        void* p = (void*)w;
        w += (nbytes + 255) & ~(size_t)255;
        return p;
    };
    float* h0    = (float*)alloc((size_t)NN * CC * 4);
    float* h1    = (float*)alloc((size_t)NN * CC * 3 * 4);
    float* r_e   = (float*)alloc((size_t)E * 4);
    float* rhat  = (float*)alloc((size_t)E * 3 * 4);
    float* m0buf = (float*)alloc((size_t)E * CC * 4);
    float* m1buf = (float*)alloc((size_t)E * CC * 3 * 4);
    int* deg     = (int*)alloc((size_t)NN * 4);
    int* rowptr  = (int*)alloc((size_t)(NN + 1) * 4);
    int* cursor  = (int*)alloc((size_t)NN * 4);
    int* einc    = (int*)alloc((size_t)E * 4);

    const int TB = 256;
    k_zero_int<<<(NN + TB - 1) / TB, TB, 0, stream>>>(deg, NN);
    k_init_h0<<<NN, 64, 0, stream>>>(seq, Win0, h0);
    k_init_h1<<<(NN * CC + TB - 1) / TB, TB, 0, stream>>>(x, Win1, h1);
    k_geom<<<(E + TB - 1) / TB, TB, 0, stream>>>(src, dst, x, r_e, rhat, E);
    k_count<<<(E + TB - 1) / TB, TB, 0, stream>>>(dst, deg, E);
    k_scan<<<1, 64, 0, stream>>>(deg, rowptr, cursor);
    k_scatter<<<(E + TB - 1) / TB, TB, 0, stream>>>(dst, rowptr, cursor, einc, E);

    for (int l = 0; l < NLAYER; ++l) {
        k_edge_msg<<<(E + WPB - 1) / WPB, 64 * WPB, 0, stream>>>(
            l, E, src, dst, pair, bppm, r_e, rhat, h0, h1,
            Wr1, br1, Wr2, br2, Wm00, Wm01, Wm10, Wm11, m0buf, m1buf);
        k_node<<<NN, 64, 0, stream>>>(l, rowptr, einc, m0buf, m1buf, h0, h1,
                                      Wq, Ws0, Ws1, gam0, bet0, gam1);
    }
    k_out<<<(NN * 3 + TB - 1) / TB, TB, 0, stream>>>(x, h1, Wout, (float*)d_out);
}

// Round 2
// 899.707 us; speedup vs baseline: 1.6447x; 1.6447x over previous
//
#include <hip/hip_runtime.h>
#include <hip/hip_bf16.h>
#include <math.h>

#define BB 4
#define LL 512
#define D0 640
#define PP 128
#define CC 32
#define NLAYER 3
#define NN (BB*LL)      // 2048
#define RADIN 130

typedef __attribute__((ext_vector_type(8))) short bf16x8;
typedef __attribute__((ext_vector_type(4))) float f32x4;

__device__ __forceinline__ short f2b(float v) {
    __hip_bfloat16 h = __float2bfloat16(v);
    short s; __builtin_memcpy(&s, &h, 2); return s;
}

// ---------------- utility kernels ----------------

__global__ void k_zero_int(int* __restrict__ p, int n) {
    int i = blockIdx.x * blockDim.x + threadIdx.x;
    if (i < n) p[i] = 0;
}

// h0 = seq_rep @ Win0   (one wave per node; lanes 0..31 chan, halves split K)
__global__ __launch_bounds__(64) void k_init_h0(const float* __restrict__ seq,
                                                const float* __restrict__ Win0,
                                                float* __restrict__ h0) {
    const int n = blockIdx.x, lane = threadIdx.x;
    const int c = lane & 31, half = lane >> 5;
    const float* s = seq + (size_t)n * D0;
    float acc = 0.f;
    const int i0 = half * (D0 / 2), i1 = i0 + (D0 / 2);
    for (int i = i0; i < i1; ++i) acc = fmaf(s[i], Win0[i * CC + c], acc);
    acc += __shfl_xor(acc, 32);
    if (lane < 32) h0[n * CC + c] = acc;
}

// h1[n,c,d] = x[n,d] * Win1[c]
__global__ void k_init_h1(const float* __restrict__ x, const float* __restrict__ Win1,
                          float* __restrict__ h1) {
    int idx = blockIdx.x * blockDim.x + threadIdx.x;
    if (idx >= NN * CC) return;
    int n = idx >> 5, c = idx & 31;
    float w = Win1[c];
    const float* xp = x + n * 3;
    float* hp = h1 + (size_t)n * 96 + c * 3;
    hp[0] = xp[0] * w; hp[1] = xp[1] * w; hp[2] = xp[2] * w;
}

// per-edge geometry: r, rhat
__global__ void k_geom(const int* __restrict__ src, const int* __restrict__ dst,
                       const float* __restrict__ x, float* __restrict__ r_e,
                       float* __restrict__ rhat, int E) {
    int e = blockIdx.x * blockDim.x + threadIdx.x;
    if (e >= E) return;
    int s = src[e], d = dst[e];
    float dx = x[d * 3 + 0] - x[s * 3 + 0];
    float dy = x[d * 3 + 1] - x[s * 3 + 1];
    float dz = x[d * 3 + 2] - x[s * 3 + 2];
    float r = sqrtf(dx * dx + dy * dy + dz * dz + 1e-12f);
    float ir = 1.f / (r + 1e-8f);
    r_e[e] = r;
    rhat[e * 3 + 0] = dx * ir; rhat[e * 3 + 1] = dy * ir; rhat[e * 3 + 2] = dz * ir;
}

__global__ void k_count(const int* __restrict__ dst, int* __restrict__ deg, int E) {
    int e = blockIdx.x * blockDim.x + threadIdx.x;
    if (e < E) atomicAdd(&deg[dst[e]], 1);
}

// exclusive scan over N=2048 degrees with one wave; also zero cursor
__global__ __launch_bounds__(64) void k_scan(const int* __restrict__ deg,
                                             int* __restrict__ rowptr,
                                             int* __restrict__ cursor) {
    const int lane = threadIdx.x;          // 0..63
    const int base = lane * 32;            // 64*32 = 2048
    int loc[32]; int s = 0;
    for (int i = 0; i < 32; ++i) { loc[i] = deg[base + i]; s += loc[i]; }
    int pre = s;
    for (int off = 1; off < 64; off <<= 1) {
        int t = __shfl_up(pre, off);
        if (lane >= off) pre += t;
    }
    pre -= s;
    int run = pre;
    for (int i = 0; i < 32; ++i) { rowptr[base + i] = run; cursor[base + i] = 0; run += loc[i]; }
    if (lane == 63) rowptr[NN] = run;
}

__global__ void k_scatter(const int* __restrict__ dst, const int* __restrict__ rowptr,
                          int* __restrict__ cursor, int* __restrict__ einc, int E) {
    int e = blockIdx.x * blockDim.x + threadIdx.x;
    if (e >= E) return;
    int d = dst[e];
    int pos = atomicAdd(&cursor[d], 1);
    einc[rowptr[d] + pos] = e;
}

// build bf16 ef rows [E][160] (pad 130->160 with zeros); one wave per edge
__global__ __launch_bounds__(256) void k_build_ef(
    const int* __restrict__ src, const int* __restrict__ dst,
    const float* __restrict__ pair, const float* __restrict__ bppm,
    const float* __restrict__ r_e, short* __restrict__ efb, int E)
{
    int e = blockIdx.x * 4 + (threadIdx.x >> 6);
    int lane = threadIdx.x & 63;
    if (e >= E) return;
    int s = src[e], d = dst[e];
    int b = s / LL, si = s % LL, di = d % LL;
    size_t prow = ((size_t)b * LL + si) * LL + di;
    const float* pr = pair + prow * PP;
    short* out = efb + (size_t)e * 160;
    out[lane] = f2b(pr[lane]);
    out[64 + lane] = f2b(pr[64 + lane]);
    if (lane < 32) {
        int idx = 128 + lane;
        float v = 0.f;
        if (idx == 128) v = bppm[prow];
        else if (idx == 129) v = r_e[e];
        out[idx] = f2b(v);
    }
}

// pack Wr1/Wr2 into MFMA B-fragment order (bf16)
// W1p: [NL][5][4][64][8] ; W2p: [NL][2][8][64][8]
__global__ void k_pack(const float* __restrict__ Wr1, const float* __restrict__ Wr2,
                       short* __restrict__ W1p, short* __restrict__ W2p) {
    int t = blockIdx.x * blockDim.x + threadIdx.x;
    const int tot1 = NLAYER * 5 * 4 * 64 * 8;
    const int tot2 = NLAYER * 2 * 8 * 64 * 8;
    if (t < tot1) {
        int j = t & 7; int r = t >> 3;
        int ln = r & 63; r >>= 6;
        int cb = r & 3; r >>= 2;
        int kb = r % 5; int l = r / 5;
        int row = kb * 32 + (ln >> 4) * 8 + j;
        int col = cb * 16 + (ln & 15);
        float v = (row < RADIN) ? Wr1[((size_t)l * RADIN + row) * 64 + col] : 0.f;
        W1p[t] = f2b(v);
    } else if (t < tot1 + tot2) {
        int t2 = t - tot1;
        int j = t2 & 7; int r = t2 >> 3;
        int ln = r & 63; r >>= 6;
        int cb = r & 7; r >>= 3;
        int kb = r & 1; int l = r >> 1;
        int row = kb * 32 + (ln >> 4) * 8 + j;
        int col = cb * 16 + (ln & 15);
        W2p[t2] = f2b(Wr2[((size_t)l * 64 + row) * 128 + col]);
    }
}

// ---------------- per-layer node precompute ----------------
// q = h0@Wq, P00 = h0@Wm00, P10 = h0@Wm10, P11[n,f,d] = sum_c h1[n,c,d]*Wm11[c,f]
__global__ __launch_bounds__(256) void k_nodepre(
    int l, const float* __restrict__ h0, const float* __restrict__ h1,
    const float* __restrict__ Wq, const float* __restrict__ Wm00,
    const float* __restrict__ Wm10, const float* __restrict__ Wm11,
    float* __restrict__ qbuf, float* __restrict__ P00,
    float* __restrict__ P10, float* __restrict__ P11)
{
    __shared__ float sh0[8][32], sh1[8][96];
    const int c = threadIdx.x & 31, hw = threadIdx.x >> 5;
    const int n = blockIdx.x * 8 + hw;
    sh0[hw][c] = h0[n * CC + c];
    const float* hp = h1 + (size_t)n * 96 + c * 3;
    sh1[hw][c * 3 + 0] = hp[0]; sh1[hw][c * 3 + 1] = hp[1]; sh1[hw][c * 3 + 2] = hp[2];
    // half-wave local LDS: same-wave ordering suffices
    const float* WqL  = Wq   + l * 1024;
    const float* W00L = Wm00 + l * 1024;
    const float* W10L = Wm10 + l * 1024;
    const float* W11L = Wm11 + l * 1024;
    float q = 0.f, p00 = 0.f, p10 = 0.f, px = 0.f, py = 0.f, pz = 0.f;
    for (int i = 0; i < 32; ++i) {
        float a = sh0[hw][i];
        q   = fmaf(a, WqL[i * 32 + c], q);
        p00 = fmaf(a, W00L[i * 32 + c], p00);
        p10 = fmaf(a, W10L[i * 32 + c], p10);
        float w = W11L[i * 32 + c];
        px = fmaf(sh1[hw][i * 3 + 0], w, px);
        py = fmaf(sh1[hw][i * 3 + 1], w, py);
        pz = fmaf(sh1[hw][i * 3 + 2], w, pz);
    }
    qbuf[n * 32 + c] = q; P00[n * 32 + c] = p00; P10[n * 32 + c] = p10;
    float* pp = P11 + (size_t)n * 96 + c * 3;
    pp[0] = px; pp[1] = py; pp[2] = pz;
}

// ---------------- radial MLP via MFMA (fused 2 GEMMs) ----------------
// block = 256 thr = 4 waves; block tile = 64 edges; wave tile = 16 edges
__global__ __launch_bounds__(256) void k_radial(
    int l, int E,
    const short* __restrict__ efb,       // [E][160] bf16
    const short* __restrict__ W1p,       // [NL][5][4][64][8]
    const short* __restrict__ W2p,       // [NL][2][8][64][8]
    const float* __restrict__ br1,       // [NL][64]
    const float* __restrict__ br2,       // [NL][128]
    float* __restrict__ rad)             // [E][128]
{
    __shared__ short s_hid[4][16][72];   // per-wave [16][64] padded to 72
    const int lane = threadIdx.x & 63, wv = threadIdx.x >> 6;
    const int r16 = lane & 15, q4 = lane >> 4;
    const int e0 = blockIdx.x * 64 + wv * 16;

    // ---- GEMM1: [16 x 160] @ [160 x 64] ----
    f32x4 acc0 = {0.f,0.f,0.f,0.f}, acc1 = {0.f,0.f,0.f,0.f};
    f32x4 acc2 = {0.f,0.f,0.f,0.f}, acc3 = {0.f,0.f,0.f,0.f};
    int row = e0 + r16; if (row >= E) row = E - 1;
    const short* arow = efb + (size_t)row * 160 + q4 * 8;
    const short* b1b = W1p + (size_t)l * (5 * 4 * 64 * 8) + lane * 8;
    for (int kb = 0; kb < 5; ++kb) {
        bf16x8 af = *(const bf16x8*)(arow + kb * 32);
        const short* bp = b1b + kb * (4 * 64 * 8);
        bf16x8 b0 = *(const bf16x8*)(bp);
        bf16x8 b1v = *(const bf16x8*)(bp + 64 * 8);
        bf16x8 b2v = *(const bf16x8*)(bp + 2 * 64 * 8);
        bf16x8 b3v = *(const bf16x8*)(bp + 3 * 64 * 8);
        acc0 = __builtin_amdgcn_mfma_f32_16x16x32_bf16(af, b0,  acc0, 0, 0, 0);
        acc1 = __builtin_amdgcn_mfma_f32_16x16x32_bf16(af, b1v, acc1, 0, 0, 0);
        acc2 = __builtin_amdgcn_mfma_f32_16x16x32_bf16(af, b2v, acc2, 0, 0, 0);
        acc3 = __builtin_amdgcn_mfma_f32_16x16x32_bf16(af, b3v, acc3, 0, 0, 0);
    }
    // bias + relu + stash to LDS as bf16  (C/D: col=lane&15, row=(lane>>4)*4+i)
    {
        f32x4 a[4] = {acc0, acc1, acc2, acc3};
        for (int cb = 0; cb < 4; ++cb) {
            int col = cb * 16 + r16;
            float b = br1[l * 64 + col];
            for (int i = 0; i < 4; ++i) {
                float v = fmaxf(a[cb][i] + b, 0.f);
                s_hid[wv][q4 * 4 + i][col] = f2b(v);
            }
        }
    }
    // ---- GEMM2: [16 x 64] @ [64 x 128] ----
    f32x4 o[8];
    for (int cb = 0; cb < 8; ++cb) { o[cb].x=0.f; o[cb].y=0.f; o[cb].z=0.f; o[cb].w=0.f; }
    const short* b2b = W2p + (size_t)l * (2 * 8 * 64 * 8) + lane * 8;
    for (int kb = 0; kb < 2; ++kb) {
        bf16x8 af = *(const bf16x8*)(&s_hid[wv][r16][kb * 32 + q4 * 8]);
        const short* bp = b2b + kb * (8 * 64 * 8);
        for (int cb = 0; cb < 8; ++cb) {
            bf16x8 bf = *(const bf16x8*)(bp + cb * (64 * 8));
            o[cb] = __builtin_amdgcn_mfma_f32_16x16x32_bf16(af, bf, o[cb], 0, 0, 0);
        }
    }
    for (int cb = 0; cb < 8; ++cb) {
        int col = cb * 16 + r16;
        float b = br2[l * 128 + col];
        for (int i = 0; i < 4; ++i) {
            int er = e0 + q4 * 4 + i;
            if (er < E) rad[(size_t)er * 128 + col] = o[cb][i] + b;
        }
    }
}

// ---------------- edge epilogue: m0, m1 ----------------
// half-wave per edge; Wm01 staged in LDS per block
__global__ __launch_bounds__(256) void k_edge2(
    int l, int E, const int* __restrict__ src, const float* __restrict__ rhat,
    const float* __restrict__ rad, const float* __restrict__ h1,
    const float* __restrict__ Wm01, const float* __restrict__ P00,
    const float* __restrict__ P10, const float* __restrict__ P11,
    float* __restrict__ m0buf, float* __restrict__ m1buf)
{
    __shared__ float sW[1024];
    for (int i = threadIdx.x; i < 1024; i += 256) sW[i] = Wm01[l * 1024 + i];
    __syncthreads();
    const int e = blockIdx.x * 8 + (threadIdx.x >> 5);
    if (e >= E) return;
    const int c = threadIdx.x & 31;
    const int lane = threadIdx.x & 63;
    const int base = lane & 32;
    const int s = src[e];
    float r0 = rhat[e * 3 + 0], r1 = rhat[e * 3 + 1], r2 = rhat[e * 3 + 2];
    const float* hp = h1 + (size_t)s * 96 + c * 3;
    float dot = hp[0] * r0 + hp[1] * r1 + hp[2] * r2;
    float t1 = 0.f;
    for (int i = 0; i < 32; ++i) {
        float di = __shfl(dot, base + i);
        t1 = fmaf(di, sW[i * 32 + c], t1);
    }
    const float* rp = rad + (size_t)e * 128;
    float w00 = rp[c], w01 = rp[32 + c], w10 = rp[64 + c], w11 = rp[96 + c];
    m0buf[(size_t)e * 32 + c] = fmaf(w00, P00[s * 32 + c], w01 * t1);
    float u10 = w10 * P10[s * 32 + c];
    const float* pp = P11 + (size_t)s * 96 + c * 3;
    float* mp = m1buf + (size_t)e * 96 + c * 3;
    mp[0] = fmaf(w11, pp[0], u10 * r0);
    mp[1] = fmaf(w11, pp[1], u10 * r1);
    mp[2] = fmaf(w11, pp[2], u10 * r2);
}

// ---------------- node update kernel (per layer) ----------------
__global__ __launch_bounds__(64) void k_node(
    int l, const int* __restrict__ rowptr, const int* __restrict__ einc,
    const float* __restrict__ m0buf, const float* __restrict__ m1buf,
    const float* __restrict__ qbuf,
    float* __restrict__ h0, float* __restrict__ h1,
    const float* __restrict__ Ws0, const float* __restrict__ Ws1,
    const float* __restrict__ gam0, const float* __restrict__ bet0,
    const float* __restrict__ gam1)
{
    const int n = blockIdx.x, lane = threadIdx.x;
    const int c = lane & 31, half = lane >> 5;
    __shared__ float s_h0[32], s_a0[32], s_a1[96];
    if (lane < 32) s_h0[lane] = h0[n * CC + lane];
    __syncthreads();

    float qc = qbuf[n * 32 + c];

    float m_run = -INFINITY, l_run = 0.f;
    float a0 = 0.f, a1x = 0.f, a1y = 0.f, a1z = 0.f;
    const int st = rowptr[n], en = rowptr[n + 1];
    for (int i = st; i < en; i += 2) {
        const int idx = i + half;
        const bool valid = idx < en;
        float kc = 0.f, mv0 = 0.f, mv1 = 0.f, mv2 = 0.f;
        if (valid) {
            const int e = einc[idx];
            kc = m0buf[(size_t)e * 32 + c];
            const float* mp = m1buf + (size_t)e * 96 + c * 3;
            mv0 = mp[0]; mv1 = mp[1]; mv2 = mp[2];
        }
        float p = qc * kc;
        p += __shfl_xor(p, 1); p += __shfl_xor(p, 2); p += __shfl_xor(p, 4);
        if (valid) {
            float logit = p * 0.35355339059327373f;   // 1/sqrt(8)
            float mn = fmaxf(m_run, logit);
            float sc = __expf(m_run - mn);
            float w  = __expf(logit - mn);
            l_run = fmaf(l_run, sc, w);
            a0  = fmaf(a0,  sc, w * kc);
            a1x = fmaf(a1x, sc, w * mv0);
            a1y = fmaf(a1y, sc, w * mv1);
            a1z = fmaf(a1z, sc, w * mv2);
            m_run = mn;
        }
    }
    float m_o  = __shfl_xor(m_run, 32), l_o = __shfl_xor(l_run, 32);
    float a0o  = __shfl_xor(a0, 32);
    float a1xo = __shfl_xor(a1x, 32), a1yo = __shfl_xor(a1y, 32), a1zo = __shfl_xor(a1z, 32);
    float mn = fmaxf(m_run, m_o);
    float sa = 0.f, sb = 0.f;
    if (mn > -INFINITY) { sa = __expf(m_run - mn); sb = __expf(m_o - mn); }
    float den = l_run * sa + l_o * sb;
    float inv = 1.0f / (den + 1e-9f);
    float g0c = (a0  * sa + a0o  * sb) * inv;
    float g1x = (a1x * sa + a1xo * sb) * inv;
    float g1y = (a1y * sa + a1yo * sb) * inv;
    float g1z = (a1z * sa + a1zo * sb) * inv;
    if (lane < 32) {
        s_a0[c] = g0c;
        s_a1[c * 3 + 0] = g1x; s_a1[c * 3 + 1] = g1y; s_a1[c * 3 + 2] = g1z;
    }
    __syncthreads();

    float x0 = s_h0[c];
    {
        const float* W = Ws0 + l * 1024;
        for (int i = 0; i < 32; ++i) x0 = fmaf(s_a0[i], W[i * 32 + c], x0);
    }
    float mu = x0;
    mu += __shfl_xor(mu, 1); mu += __shfl_xor(mu, 2); mu += __shfl_xor(mu, 4);
    mu += __shfl_xor(mu, 8); mu += __shfl_xor(mu, 16);
    mu *= (1.f / 32.f);
    float sq = x0 * x0;
    sq += __shfl_xor(sq, 1); sq += __shfl_xor(sq, 2); sq += __shfl_xor(sq, 4);
    sq += __shfl_xor(sq, 8); sq += __shfl_xor(sq, 16);
    float var = sq * (1.f / 32.f) - mu * mu;
    float h0n = (x0 - mu) * rsqrtf(var + 1e-5f) * gam0[l * 32 + c] + bet0[l * 32 + c];
    if (lane < 32) h0[n * CC + c] = h0n;

    const float* hp = h1 + (size_t)n * 96 + c * 3;
    float v0 = hp[0], v1 = hp[1], v2 = hp[2];
    {
        const float* W = Ws1 + l * 1024;
        for (int i = 0; i < 32; ++i) {
            float w = W[i * 32 + c];
            v0 = fmaf(s_a1[i * 3 + 0], w, v0);
            v1 = fmaf(s_a1[i * 3 + 1], w, v1);
            v2 = fmaf(s_a1[i * 3 + 2], w, v2);
        }
    }
    float nrm = sqrtf(v0 * v0 + v1 * v1 + v2 * v2 + 1e-12f);
    float mu2 = nrm;
    mu2 += __shfl_xor(mu2, 1); mu2 += __shfl_xor(mu2, 2); mu2 += __shfl_xor(mu2, 4);
    mu2 += __shfl_xor(mu2, 8); mu2 += __shfl_xor(mu2, 16);
    mu2 *= (1.f / 32.f);
    float sq2 = nrm * nrm;
    sq2 += __shfl_xor(sq2, 1); sq2 += __shfl_xor(sq2, 2); sq2 += __shfl_xor(sq2, 4);
    sq2 += __shfl_xor(sq2, 8); sq2 += __shfl_xor(sq2, 16);
    float var2 = sq2 * (1.f / 32.f) - mu2 * mu2;
    float nln = (nrm - mu2) * rsqrtf(var2 + 1e-5f) * gam1[l * 32 + c];
    float scl = nln / (nrm + 1e-8f);
    if (lane < 32) {
        float* hw = h1 + (size_t)n * 96 + c * 3;
        hw[0] = v0 * scl; hw[1] = v1 * scl; hw[2] = v2 * scl;
    }
}

// ---------------- output kernel ----------------
__global__ void k_out(const float* __restrict__ x, const float* __restrict__ h1,
                      const float* __restrict__ Wout, float* __restrict__ out) {
    int idx = blockIdx.x * blockDim.x + threadIdx.x;   // N*3
    if (idx >= NN * 3) return;
    int n = idx / 3, d = idx % 3;
    float acc = x[idx];
    const float* hp = h1 + (size_t)n * 96 + d;
    for (int cc = 0; cc < 32; ++cc) acc = fmaf(hp[cc * 3], Wout[cc], acc);
    out[idx] = acc;
}

// ---------------- launch ----------------
extern "C" void kernel_launch(void* const* d_in, const int* in_sizes, int n_in,
                              void* d_out, int out_size, void* d_ws, size_t ws_size,
                              hipStream_t stream) {
    const float* seq  = (const float*)d_in[0];
    const float* pair = (const float*)d_in[1];
    const float* bppm = (const float*)d_in[2];
    const float* x    = (const float*)d_in[3];
    const int*   src  = (const int*)d_in[4];
    const int*   dst  = (const int*)d_in[5];
    const float* Win0 = (const float*)d_in[6];
    const float* Win1 = (const float*)d_in[7];
    const float* Wr1  = (const float*)d_in[8];
    const float* br1  = (const float*)d_in[9];
    const float* Wr2  = (const float*)d_in[10];
    const float* br2  = (const float*)d_in[11];
    const float* Wm00 = (const float*)d_in[12];
    const float* Wm01 = (const float*)d_in[13];
    const float* Wm10 = (const float*)d_in[14];
    const float* Wm11 = (const float*)d_in[15];
    const float* Wq   = (const float*)d_in[16];
    const float* Ws0  = (const float*)d_in[17];
    const float* Ws1  = (const float*)d_in[18];
    const float* gam0 = (const float*)d_in[19];
    const float* bet0 = (const float*)d_in[20];
    const float* gam1 = (const float*)d_in[21];
    const float* Wout = (const float*)d_in[22];
    const int E = in_sizes[4];

    char* w = (char*)d_ws;
    auto alloc = [&](size_t nbytes) {
        void* p = (void*)w;
        w += (nbytes + 255) & ~(size_t)255;
        return p;
    };
    float* h0    = (float*)alloc((size_t)NN * CC * 4);
    float* h1    = (float*)alloc((size_t)NN * CC * 3 * 4);
    float* r_e   = (float*)alloc((size_t)E * 4);
    float* rhat  = (float*)alloc((size_t)E * 3 * 4);
    float* m0buf = (float*)alloc((size_t)E * CC * 4);
    float* m1buf = (float*)alloc((size_t)E * CC * 3 * 4);
    int* deg     = (int*)alloc((size_t)NN * 4);
    int* rowptr  = (int*)alloc((size_t)(NN + 1) * 4);
    int* cursor  = (int*)alloc((size_t)NN * 4);
    int* einc    = (int*)alloc((size_t)E * 4);
    short* efb   = (short*)alloc((size_t)E * 160 * 2);
    short* W1p   = (short*)alloc((size_t)NLAYER * 5 * 4 * 64 * 8 * 2);
    short* W2p   = (short*)alloc((size_t)NLAYER * 2 * 8 * 64 * 8 * 2);
    float* rad   = (float*)alloc((size_t)E * 128 * 4);
    float* qbuf  = (float*)alloc((size_t)NN * 32 * 4);
    float* P00   = (float*)alloc((size_t)NN * 32 * 4);
    float* P10   = (float*)alloc((size_t)NN * 32 * 4);
    float* P11   = (float*)alloc((size_t)NN * 96 * 4);

    const int TB = 256;
    k_zero_int<<<(NN + TB - 1) / TB, TB, 0, stream>>>(deg, NN);
    k_init_h0<<<NN, 64, 0, stream>>>(seq, Win0, h0);
    k_init_h1<<<(NN * CC + TB - 1) / TB, TB, 0, stream>>>(x, Win1, h1);
    k_geom<<<(E + TB - 1) / TB, TB, 0, stream>>>(src, dst, x, r_e, rhat, E);
    k_count<<<(E + TB - 1) / TB, TB, 0, stream>>>(dst, deg, E);
    k_scan<<<1, 64, 0, stream>>>(deg, rowptr, cursor);
    k_scatter<<<(E + TB - 1) / TB, TB, 0, stream>>>(dst, rowptr, cursor, einc, E);
    k_build_ef<<<(E + 3) / 4, 256, 0, stream>>>(src, dst, pair, bppm, r_e, efb, E);
    {
        int tot = NLAYER * 5 * 4 * 64 * 8 + NLAYER * 2 * 8 * 64 * 8;
        k_pack<<<(tot + TB - 1) / TB, TB, 0, stream>>>(Wr1, Wr2, W1p, W2p);
    }

    for (int l = 0; l < NLAYER; ++l) {
        k_nodepre<<<NN / 8, 256, 0, stream>>>(l, h0, h1, Wq, Wm00, Wm10, Wm11,
                                              qbuf, P00, P10, P11);
        k_radial<<<(E + 63) / 64, 256, 0, stream>>>(l, E, efb, W1p, W2p, br1, br2, rad);
        k_edge2<<<(E + 7) / 8, 256, 0, stream>>>(l, E, src, rhat, rad, h1, Wm01,
                                                 P00, P10, P11, m0buf, m1buf);
        k_node<<<NN, 64, 0, stream>>>(l, rowptr, einc, m0buf, m1buf, qbuf, h0, h1,
                                      Ws0, Ws1, gam0, bet0, gam1);
    }
    k_out<<<(NN * 3 + TB - 1) / TB, TB, 0, stream>>>(x, h1, Wout, (float*)d_out);
}